// Round 4
// baseline (142.483 us; speedup 1.0000x reference)
//
#include <hip/hip_runtime.h>

typedef unsigned short u16;
typedef unsigned int   u32;

typedef __attribute__((ext_vector_type(8))) short short8;
typedef __attribute__((ext_vector_type(4))) float floatx4;
typedef __attribute__((ext_vector_type(2))) float v2f;

// ---- f32 -> bf16 (RNE) ----
__device__ __forceinline__ u16 f2bf(float f) {
    u32 u = __float_as_uint(f);
    u = u + 0x7fffu + ((u >> 16) & 1u);
    return (u16)(u >> 16);
}

// pack two f32 -> two bf16 (round-to-nearest-away) in one v_perm
__device__ __forceinline__ u32 pack2bf(float s0, float s1) {
    u32 a = __float_as_uint(s0) + 0x8000u;
    u32 b = __float_as_uint(s1) + 0x8000u;
    return __builtin_amdgcn_perm(b, a, 0x07060302u);  // {b.hi16, a.hi16}
}

__device__ __forceinline__ floatx4 mfma16(short8 a, short8 b, floatx4 c) {
    return __builtin_amdgcn_mfma_f32_16x16x32_bf16(a, b, c, 0, 0, 0);
}

// ---- prep: build per-thread B-fragment streams (all for 512-thread blocks now).
// W1frag: [kt*8192 + t*16 + j*8 + ji] = bf16(W1[(7+kt*32+lq*8+ji)*256 + w*32+j*16+lr])
// W2frag: [kt*8192 + t*16 + j*8 + ji] = bf16(W2[(kt*32+lq*8+ji)*256 + w*32+j*16+lr])
// W3frag: [kt*4096 + t*8 + ji]        = bf16(W3[(kt*32+lq*8+ji)*128 + w*16+lr])
__global__ void k_prep(const float* __restrict__ W1, const float* __restrict__ W2,
                       const float* __restrict__ W3, u16* __restrict__ W1frag,
                       u16* __restrict__ W2frag, u16* __restrict__ W3frag) {
    int idx = blockIdx.x * 256 + threadIdx.x;
    if (idx < 524288) {
        int kt = idx >> 13, r = idx & 8191;
        int t = r >> 4, j = (r >> 3) & 1, ji = r & 7;
        int lane = t & 63, w = t >> 6, lr = lane & 15, lq = lane >> 4;
        W1frag[idx] = f2bf(W1[(7 + kt * 32 + lq * 8 + ji) * 256 + w * 32 + j * 16 + lr]);
    } else if (idx < 589824) {
        int i = idx - 524288;
        int kt = i >> 13, r = i & 8191;
        int t = r >> 4, j = (r >> 3) & 1, ji = r & 7;
        int lane = t & 63, w = t >> 6, lr = lane & 15, lq = lane >> 4;
        W2frag[i] = f2bf(W2[(kt * 32 + lq * 8 + ji) * 256 + w * 32 + j * 16 + lr]);
    } else if (idx < 622592) {
        int i = idx - 589824;
        int kt = i >> 12, r = i & 4095;
        int t = r >> 3, ji = r & 7;
        int lane = t & 63, w = t >> 6, lr = lane & 15, lq = lane >> 4;
        W3frag[i] = f2bf(W3[(kt * 32 + lq * 8 + ji) * 128 + w * 16 + lr]);
    }
}

// ---- fully fused: h1 (dots GEMM) -> h2 -> fk -> x-reduce, one block per 64 rows.
// 512 threads (8 waves). Main GEMM identical to round-3 k_h1 (K=64 superstep,
// swizzled As, conflict-free, no spill). h1 never leaves the block: epilogue
// writes it to LDS (h1s overlays the then-dead xls+As region), phase 1 computes
// h2 = lrelu(h1s@W2+b2) -> h2s, phase 2 fk = h2s@W3+b3 fused with the x outer-
// product reduce. Removes the 16.8MB h1 HBM write + 4x16.8MB k_tail re-read +
// one dependent launch.
// LDS map (76288 B total, 2 blocks/CU):
//   [0,40960)     main: xls f32[6144] | As u16[2][64][64]
//                 tail: h1s u16[64][264] @0 | xs f32[64][4] @33792 | red f32[128][4] @34816
//   [40960,42496) rowsml f32[64][6]
//   [42496,76288) h2s u16[64][264]
__global__ __launch_bounds__(512, 4) void k_fused(
    const float* __restrict__ x, const float* __restrict__ u,
    const float* __restrict__ basis, const float* __restrict__ W1,
    const float* __restrict__ b1, const float* __restrict__ b2,
    const float* __restrict__ b3, const u16* __restrict__ W1frag,
    const u16* __restrict__ W2frag, const u16* __restrict__ W3frag,
    float* __restrict__ out) {
    __shared__ __align__(16) char smem[76288];
    float* xls = (float*)smem;                       // SoA x: X/Y/Z 2048 each
    char* Asb = smem + 24576;                        // swizzled dots tile
    u16 (*h1s)[264] = (u16(*)[264])smem;             // tail overlay
    float (*xsm)[4] = (float(*)[4])(smem + 33792);
    float (*redm)[4] = (float(*)[4])(smem + 34816);
    float (*rowsml)[6] = (float(*)[6])(smem + 40960);
    u16 (*h2s)[264] = (u16(*)[264])(smem + 42496);

    const int t = threadIdx.x;
    const int b = blockIdx.y;
    const int i0 = blockIdx.x * 64;
    const int lane = t & 63, w = t >> 6;
    const int lr = lane & 15, lq = lane >> 4;

    // build SoA copy of x[b] (coalesced read, scalar LDS scatter; one-time)
    {
        const float4* src = (const float4*)(x + b * 6144);
#pragma unroll
        for (int kk = 0; kk < 3; ++kk) {
            int q = t + kk * 512;
            float4 v = src[q];
            float vv[4] = {v.x, v.y, v.z, v.w};
            int e = q * 4;
#pragma unroll
            for (int cc = 0; cc < 4; ++cc) {
                int ee = e + cc;
                xls[(ee % 3) * 2048 + ee / 3] = vv[cc];
            }
        }
    }
    __syncthreads();
    if (t < 64) {
        float xx = xls[i0 + t], xy = xls[2048 + i0 + t], xz = xls[4096 + i0 + t];
        rowsml[t][0] = sqrtf(xx * xx + xy * xy + xz * xz);
#pragma unroll
        for (int p = 0; p < 4; ++p) {
            const float* bp = basis + (b * 4 + p) * 3;
            rowsml[t][1 + p] = xx * bp[0] + xy * bp[1] + xz * bp[2];
        }
    }
    const float ax = xls[i0 + lane];
    const float ay = xls[2048 + i0 + lane];
    const float az = xls[4096 + i0 + lane];
    const u16* wf = W1frag + t * 16;
    const float4* X4 = (const float4*)xls;  // [0..512) X, [512..1024) Y, [1024..1536) Z

    // swizzled LDS addressing (all loop-invariant); verified conflict-free (r2/r3)
    char* aswp = Asb + lane * 128 + ((w ^ (lane & 7)) << 4);   // write ptr, buf0
    int ro[4];
    {
        int sl = (lq ^ (lr & 7));
#pragma unroll
        for (int i = 0; i < 4; ++i)
            ro[i] = (i * 16 + lr) * 128 + (sl << 4);           // kk=0; kk=1 is ^64
    }

    // generate 8 dots (cols s*64 + w*8 ..+8) for superstep s into As[buf]
    auto gen_store = [&](int s, int buf) {
        int q = s * 16 + w * 2;                   // wave-uniform -> LDS broadcast
        v2f dA, dB, dC, dD;
        {
            float4 a0 = X4[q], a1 = X4[q + 1];
            v2f t0 = {a0.x, a0.y}, t1 = {a0.z, a0.w};
            v2f t2 = {a1.x, a1.y}, t3 = {a1.z, a1.w};
            dA = t0 * ax; dB = t1 * ax; dC = t2 * ax; dD = t3 * ax;
        }
        {
            float4 a0 = X4[512 + q], a1 = X4[513 + q];
            v2f t0 = {a0.x, a0.y}, t1 = {a0.z, a0.w};
            v2f t2 = {a1.x, a1.y}, t3 = {a1.z, a1.w};
            dA += t0 * ay; dB += t1 * ay; dC += t2 * ay; dD += t3 * ay;
        }
        {
            float4 a0 = X4[1024 + q], a1 = X4[1025 + q];
            v2f t0 = {a0.x, a0.y}, t1 = {a0.z, a0.w};
            v2f t2 = {a1.x, a1.y}, t3 = {a1.z, a1.w};
            dA += t0 * az; dB += t1 * az; dC += t2 * az; dD += t3 * az;
        }
        float s0 = __builtin_amdgcn_sqrtf(dA.x);
        float s1 = __builtin_amdgcn_sqrtf(dA.y);
        float s2 = __builtin_amdgcn_sqrtf(dB.x);
        float s3 = __builtin_amdgcn_sqrtf(dB.y);
        float s4 = __builtin_amdgcn_sqrtf(dC.x);
        float s5 = __builtin_amdgcn_sqrtf(dC.y);
        float s6 = __builtin_amdgcn_sqrtf(dD.x);
        float s7 = __builtin_amdgcn_sqrtf(dD.y);
        uint4 dv;
        dv.x = pack2bf(s0, s1); dv.y = pack2bf(s2, s3);
        dv.z = pack2bf(s4, s5); dv.w = pack2bf(s6, s7);
        *(uint4*)(aswp + buf * 8192) = dv;
    };

    floatx4 acc[4][2];
    const floatx4 zero = {0.f, 0.f, 0.f, 0.f};
#pragma unroll
    for (int i = 0; i < 4; ++i)
#pragma unroll
        for (int j = 0; j < 2; ++j) acc[i][j] = zero;

    gen_store(0, 0);
    __syncthreads();

    {
        short8 a[4], bfr[4];
#pragma unroll 2
        for (int s = 0; s < 32; ++s) {
            const int buf = s & 1;
            const u16* wb = wf + (2 * s) * 8192;   // L2-hot B stream
            bfr[0] = *(const short8*)(wb);
            bfr[1] = *(const short8*)(wb + 8);
            bfr[2] = *(const short8*)(wb + 8192);
            bfr[3] = *(const short8*)(wb + 8192 + 8);
#pragma unroll
            for (int i = 0; i < 4; ++i)
                a[i] = *(const short8*)(Asb + buf * 8192 + ro[i]);
            if (s < 31) gen_store(s + 1, buf ^ 1);
#pragma unroll
            for (int i = 0; i < 4; ++i)
#pragma unroll
                for (int j = 0; j < 2; ++j)
                    acc[i][j] = mfma16(a[i], bfr[j], acc[i][j]);
#pragma unroll
            for (int i = 0; i < 4; ++i)
                a[i] = *(const short8*)(Asb + buf * 8192 + (ro[i] ^ 64));
#pragma unroll
            for (int i = 0; i < 4; ++i)
#pragma unroll
                for (int j = 0; j < 2; ++j)
                    acc[i][j] = mfma16(a[i], bfr[2 + j], acc[i][j]);
            __syncthreads();
        }
    }

    // ---- epilogue: h1 = small features + bias, LeakyReLU -> h1s (LDS bf16)
    // (xls/As dead after last loop barrier; h1s/xs overlay them)
    if (t < 64) { xsm[t][0] = ax; xsm[t][1] = ay; xsm[t][2] = az; }
    const int c0 = w * 32 + lr, c1 = c0 + 16;
    {
        float c0v[6], c1v[6];
        float u0 = u[b * 2 + 0], u1 = u[b * 2 + 1];
        c0v[0] = b1[c0] + u0 * W1[c0] + u1 * W1[256 + c0];
        c1v[0] = b1[c1] + u0 * W1[c1] + u1 * W1[256 + c1];
#pragma unroll
        for (int q = 1; q < 6; ++q) {
            c0v[q] = W1[(q + 1) * 256 + c0];
            c1v[q] = W1[(q + 1) * 256 + c1];
        }
#pragma unroll
        for (int i = 0; i < 4; ++i) {
#pragma unroll
            for (int r = 0; r < 4; ++r) {
                int row = i * 16 + lq * 4 + r;
                float nrm = rowsml[row][0];
                float p0 = rowsml[row][1], p1 = rowsml[row][2];
                float p2 = rowsml[row][3], p3 = rowsml[row][4];
                float v0 = acc[i][0][r] + c0v[0] + nrm * c0v[1] +
                           p0 * c0v[2] + p1 * c0v[3] + p2 * c0v[4] + p3 * c0v[5];
                v0 = v0 > 0.f ? v0 : 0.01f * v0;
                h1s[row][c0] = f2bf(v0);
                float v1 = acc[i][1][r] + c1v[0] + nrm * c1v[1] +
                           p0 * c1v[2] + p1 * c1v[3] + p2 * c1v[4] + p3 * c1v[5];
                v1 = v1 > 0.f ? v1 : 0.01f * v1;
                h1s[row][c1] = f2bf(v1);
            }
        }
    }
    __syncthreads();

    // ---- phase 1: h2 = lrelu(h1s @ W2 + b2) -> h2s
#pragma unroll
    for (int i = 0; i < 4; ++i)
#pragma unroll
        for (int j = 0; j < 2; ++j) acc[i][j] = zero;
    {
        const u16* w2s = W2frag + t * 16;
#pragma unroll 2
        for (int kt = 0; kt < 8; ++kt) {
            short8 af[4], bfr[2];
#pragma unroll
            for (int i = 0; i < 4; ++i)
                af[i] = *(const short8*)&h1s[i * 16 + lr][kt * 32 + lq * 8];
#pragma unroll
            for (int j = 0; j < 2; ++j)
                bfr[j] = *(const short8*)(w2s + kt * 8192 + j * 8);
#pragma unroll
            for (int i = 0; i < 4; ++i)
#pragma unroll
                for (int j = 0; j < 2; ++j)
                    acc[i][j] = mfma16(af[i], bfr[j], acc[i][j]);
        }
        float cb0 = b2[c0], cb1 = b2[c1];
#pragma unroll
        for (int i = 0; i < 4; ++i)
#pragma unroll
            for (int r = 0; r < 4; ++r) {
                int row = i * 16 + lq * 4 + r;
                float v0 = acc[i][0][r] + cb0;
                v0 = v0 > 0.f ? v0 : 0.01f * v0;
                h2s[row][c0] = f2bf(v0);
                float v1 = acc[i][1][r] + cb1;
                v1 = v1 > 0.f ? v1 : 0.01f * v1;
                h2s[row][c1] = f2bf(v1);
            }
    }
    __syncthreads();

    // ---- phase 2: fk = h2s @ W3 + b3, fused x outer-product reduce
    {
        floatx4 acc2[4];
#pragma unroll
        for (int i = 0; i < 4; ++i) acc2[i] = zero;
        const u16* w3s = W3frag + t * 8;
#pragma unroll 2
        for (int kt = 0; kt < 8; ++kt) {
            short8 af[4];
#pragma unroll
            for (int i = 0; i < 4; ++i)
                af[i] = *(const short8*)&h2s[i * 16 + lr][kt * 32 + lq * 8];
            short8 bfr = *(const short8*)(w3s + kt * 4096);
#pragma unroll
            for (int i = 0; i < 4; ++i) acc2[i] = mfma16(af[i], bfr, acc2[i]);
        }
        const int c3 = w * 16 + lr;
        float cb3 = b3[c3];
        float s0 = 0.f, s1 = 0.f, s2 = 0.f;
#pragma unroll
        for (int i = 0; i < 4; ++i)
#pragma unroll
            for (int r = 0; r < 4; ++r) {
                int row = i * 16 + lq * 4 + r;
                float fk = acc2[i][r] + cb3;
                s0 += fk * xsm[row][0];
                s1 += fk * xsm[row][1];
                s2 += fk * xsm[row][2];
            }
        s0 += __shfl_xor(s0, 16); s0 += __shfl_xor(s0, 32);
        s1 += __shfl_xor(s1, 16); s1 += __shfl_xor(s1, 32);
        s2 += __shfl_xor(s2, 16); s2 += __shfl_xor(s2, 32);
        if (lq == 0) {  // lanes 0..15; cols wave-exclusive
            redm[c3][0] = s0; redm[c3][1] = s1; redm[c3][2] = s2;
        }
    }
    __syncthreads();
    if (t < 128) {
#pragma unroll
        for (int d = 0; d < 3; ++d)
            atomicAdd(&out[(b * 128 + t) * 3 + d], redm[t][d] * (1.0f / 2048.0f));
    }
}

extern "C" void kernel_launch(void* const* d_in, const int* in_sizes, int n_in,
                              void* d_out, int out_size, void* d_ws, size_t ws_size,
                              hipStream_t stream) {
    const float* x     = (const float*)d_in[0];
    const float* u     = (const float*)d_in[1];
    const float* basis = (const float*)d_in[2];
    const float* W1    = (const float*)d_in[3];
    const float* b1    = (const float*)d_in[4];
    const float* W2    = (const float*)d_in[5];
    const float* b2    = (const float*)d_in[6];
    const float* W3    = (const float*)d_in[7];
    const float* b3    = (const float*)d_in[8];
    float* out = (float*)d_out;

    char* ws = (char*)d_ws;
    u16*  W1frag = (u16*)ws;                      // 1,048,576 B
    u16*  W2frag = (u16*)(ws + 1048576);          //   131,072 B
    u16*  W3frag = (u16*)(ws + 1179648);          //    65,536 B

    hipMemsetAsync(out, 0, 24576, stream);
    k_prep<<<2432, 256, 0, stream>>>(W1, W2, W3, W1frag, W2frag, W3frag);
    k_fused<<<dim3(32, 16), 512, 0, stream>>>(x, u, basis, W1, b1, b2, b3,
                                              W1frag, W2frag, W3frag, out);
}

// Round 5
// 122.021 us; speedup vs baseline: 1.1677x; 1.1677x over previous
//
#include <hip/hip_runtime.h>

typedef unsigned short u16;
typedef unsigned int   u32;

typedef __attribute__((ext_vector_type(8))) short short8;
typedef __attribute__((ext_vector_type(4))) float floatx4;
typedef __attribute__((ext_vector_type(2))) float v2f;

// ---- f32 -> bf16 (RNE) ----
__device__ __forceinline__ u16 f2bf(float f) {
    u32 u = __float_as_uint(f);
    u = u + 0x7fffu + ((u >> 16) & 1u);
    return (u16)(u >> 16);
}

// pack two f32 -> two bf16 (round-to-nearest-away) in one v_perm
__device__ __forceinline__ u32 pack2bf(float s0, float s1) {
    u32 a = __float_as_uint(s0) + 0x8000u;
    u32 b = __float_as_uint(s1) + 0x8000u;
    return __builtin_amdgcn_perm(b, a, 0x07060302u);  // {b.hi16, a.hi16}
}

__device__ __forceinline__ floatx4 mfma16(short8 a, short8 b, floatx4 c) {
    return __builtin_amdgcn_mfma_f32_16x16x32_bf16(a, b, c, 0, 0, 0);
}

// ---- prep: build per-thread B-fragment streams (512-thread consumers),
// and zero the output accumulator (replaces the hipMemsetAsync dispatch).
// W1frag: [kt*8192 + t*16 + j*8 + ji] = bf16(W1[(7+kt*32+lq*8+ji)*256 + w*32+j*16+lr])
// W2frag: [kt*8192 + t*16 + j*8 + ji] = bf16(W2[(kt*32+lq*8+ji)*256 + w*32+j*16+lr])
// W3frag: [kt*4096 + t*8 + ji]        = bf16(W3[(kt*32+lq*8+ji)*128 + w*16+lr])
__global__ void k_prep(const float* __restrict__ W1, const float* __restrict__ W2,
                       const float* __restrict__ W3, u16* __restrict__ W1frag,
                       u16* __restrict__ W2frag, u16* __restrict__ W3frag,
                       float* __restrict__ out) {
    int idx = blockIdx.x * 256 + threadIdx.x;
    if (idx < 6144) out[idx] = 0.f;
    if (idx < 524288) {
        int kt = idx >> 13, r = idx & 8191;
        int t = r >> 4, j = (r >> 3) & 1, ji = r & 7;
        int lane = t & 63, w = t >> 6, lr = lane & 15, lq = lane >> 4;
        W1frag[idx] = f2bf(W1[(7 + kt * 32 + lq * 8 + ji) * 256 + w * 32 + j * 16 + lr]);
    } else if (idx < 589824) {
        int i = idx - 524288;
        int kt = i >> 13, r = i & 8191;
        int t = r >> 4, j = (r >> 3) & 1, ji = r & 7;
        int lane = t & 63, w = t >> 6, lr = lane & 15, lq = lane >> 4;
        W2frag[i] = f2bf(W2[(kt * 32 + lq * 8 + ji) * 256 + w * 32 + j * 16 + lr]);
    } else if (idx < 622592) {
        int i = idx - 589824;
        int kt = i >> 12, r = i & 4095;
        int t = r >> 3, ji = r & 7;
        int lane = t & 63, w = t >> 6, lr = lane & 15, lq = lane >> 4;
        W3frag[i] = f2bf(W3[(kt * 32 + lq * 8 + ji) * 128 + w * 16 + lr]);
    }
}

// ---- fully fused: h1 (dots GEMM) -> h2 -> fk -> x-reduce, one block per 64 rows.
// 512 threads (8 waves). Main GEMM identical to round-3 k_h1 (K=64 superstep,
// swizzled As, conflict-free, no spill). h1 never leaves the block.
// Register discipline (round-4 spill post-mortem): ALL small per-column
// constants (W1 head, b1, u, b2, b3) are staged into colsml LDS at kernel
// start -> written immediately, nothing loop-invariant left for LICM to hoist
// across the 32-superstep main loop. No post-loop global loads anywhere.
// LDS map (76288 B total, 2 blocks/CU):
//   [0,24576)     main: xls f32[6144] (SoA X/Y/Z)
//   [24576,40960) main: As u16[2][64][64] swizzled dots tile
//     tail overlay: h1s u16[64][264] @0 (33792 B) | xsm @33792 | redm @34816
//   [40960,42496) rowsml f32[64][6]
//   [42496,76288) h2s u16[64][264] (phase 1+)
//     start/epilogue overlay: colsml f32[256][8] @42496 (8192 B) -- read in
//     epilogue BEFORE the barrier that precedes h2s writes.
__global__ __launch_bounds__(512, 4) void k_fused(
    const float* __restrict__ x, const float* __restrict__ u,
    const float* __restrict__ basis, const float* __restrict__ W1,
    const float* __restrict__ b1, const float* __restrict__ b2,
    const float* __restrict__ b3, const u16* __restrict__ W1frag,
    const u16* __restrict__ W2frag, const u16* __restrict__ W3frag,
    float* __restrict__ out) {
    __shared__ __align__(16) char smem[76288];
    float* xls = (float*)smem;                       // SoA x: X/Y/Z 2048 each
    char* Asb = smem + 24576;                        // swizzled dots tile
    u16 (*h1s)[264] = (u16(*)[264])smem;             // tail overlay
    float (*xsm)[4] = (float(*)[4])(smem + 33792);
    float (*redm)[4] = (float(*)[4])(smem + 34816);
    float (*rowsml)[6] = (float(*)[6])(smem + 40960);
    float (*colsml)[8] = (float(*)[8])(smem + 42496);
    u16 (*h2s)[264] = (u16(*)[264])(smem + 42496);

    const int t = threadIdx.x;
    const int b = blockIdx.y;
    const int i0 = blockIdx.x * 64;
    const int lane = t & 63, w = t >> 6;
    const int lr = lane & 15, lq = lane >> 4;

    // build SoA copy of x[b] (coalesced read, scalar LDS scatter; one-time)
    {
        const float4* src = (const float4*)(x + b * 6144);
#pragma unroll
        for (int kk = 0; kk < 3; ++kk) {
            int q = t + kk * 512;
            float4 v = src[q];
            float vv[4] = {v.x, v.y, v.z, v.w};
            int e = q * 4;
#pragma unroll
            for (int cc = 0; cc < 4; ++cc) {
                int ee = e + cc;
                xls[(ee % 3) * 2048 + ee / 3] = vv[cc];
            }
        }
    }
    // stage ALL small per-column constants into LDS (r3-proven; kills hoisting)
    if (t < 256) {
        int c = t;
        float u0 = u[b * 2 + 0], u1 = u[b * 2 + 1];
        colsml[c][0] = b1[c] + u0 * W1[c] + u1 * W1[256 + c];
        colsml[c][1] = W1[512 + c];
        colsml[c][2] = W1[768 + c];
        colsml[c][3] = W1[1024 + c];
        colsml[c][4] = W1[1280 + c];
        colsml[c][5] = W1[1536 + c];
        colsml[c][6] = b2[c];
        if (c < 128) colsml[c][7] = b3[c];
    }
    __syncthreads();
    if (t < 64) {
        float xx = xls[i0 + t], xy = xls[2048 + i0 + t], xz = xls[4096 + i0 + t];
        rowsml[t][0] = sqrtf(xx * xx + xy * xy + xz * xz);
#pragma unroll
        for (int p = 0; p < 4; ++p) {
            const float* bp = basis + (b * 4 + p) * 3;
            rowsml[t][1 + p] = xx * bp[0] + xy * bp[1] + xz * bp[2];
        }
    }
    const float ax = xls[i0 + lane];
    const float ay = xls[2048 + i0 + lane];
    const float az = xls[4096 + i0 + lane];
    const u16* wf = W1frag + t * 16;
    const float4* X4 = (const float4*)xls;  // [0..512) X, [512..1024) Y, [1024..1536) Z

    // swizzled LDS addressing (all loop-invariant); verified conflict-free (r2/r3)
    char* aswp = Asb + lane * 128 + ((w ^ (lane & 7)) << 4);   // write ptr, buf0
    int ro[4];
    {
        int sl = (lq ^ (lr & 7));
#pragma unroll
        for (int i = 0; i < 4; ++i)
            ro[i] = (i * 16 + lr) * 128 + (sl << 4);           // kk=0; kk=1 is ^64
    }

    // generate 8 dots (cols s*64 + w*8 ..+8) for superstep s into As[buf]
    auto gen_store = [&](int s, int buf) {
        int q = s * 16 + w * 2;                   // wave-uniform -> LDS broadcast
        v2f dA, dB, dC, dD;
        {
            float4 a0 = X4[q], a1 = X4[q + 1];
            v2f t0 = {a0.x, a0.y}, t1 = {a0.z, a0.w};
            v2f t2 = {a1.x, a1.y}, t3 = {a1.z, a1.w};
            dA = t0 * ax; dB = t1 * ax; dC = t2 * ax; dD = t3 * ax;
        }
        {
            float4 a0 = X4[512 + q], a1 = X4[513 + q];
            v2f t0 = {a0.x, a0.y}, t1 = {a0.z, a0.w};
            v2f t2 = {a1.x, a1.y}, t3 = {a1.z, a1.w};
            dA += t0 * ay; dB += t1 * ay; dC += t2 * ay; dD += t3 * ay;
        }
        {
            float4 a0 = X4[1024 + q], a1 = X4[1025 + q];
            v2f t0 = {a0.x, a0.y}, t1 = {a0.z, a0.w};
            v2f t2 = {a1.x, a1.y}, t3 = {a1.z, a1.w};
            dA += t0 * az; dB += t1 * az; dC += t2 * az; dD += t3 * az;
        }
        float s0 = __builtin_amdgcn_sqrtf(dA.x);
        float s1 = __builtin_amdgcn_sqrtf(dA.y);
        float s2 = __builtin_amdgcn_sqrtf(dB.x);
        float s3 = __builtin_amdgcn_sqrtf(dB.y);
        float s4 = __builtin_amdgcn_sqrtf(dC.x);
        float s5 = __builtin_amdgcn_sqrtf(dC.y);
        float s6 = __builtin_amdgcn_sqrtf(dD.x);
        float s7 = __builtin_amdgcn_sqrtf(dD.y);
        uint4 dv;
        dv.x = pack2bf(s0, s1); dv.y = pack2bf(s2, s3);
        dv.z = pack2bf(s4, s5); dv.w = pack2bf(s6, s7);
        *(uint4*)(aswp + buf * 8192) = dv;
    };

    floatx4 acc[4][2];
    const floatx4 zero = {0.f, 0.f, 0.f, 0.f};
#pragma unroll
    for (int i = 0; i < 4; ++i)
#pragma unroll
        for (int j = 0; j < 2; ++j) acc[i][j] = zero;

    gen_store(0, 0);
    __syncthreads();

    {
        short8 a[4], bfr[4];
#pragma unroll 2
        for (int s = 0; s < 32; ++s) {
            const int buf = s & 1;
            const u16* wb = wf + (2 * s) * 8192;   // L2-hot B stream
            bfr[0] = *(const short8*)(wb);
            bfr[1] = *(const short8*)(wb + 8);
            bfr[2] = *(const short8*)(wb + 8192);
            bfr[3] = *(const short8*)(wb + 8192 + 8);
#pragma unroll
            for (int i = 0; i < 4; ++i)
                a[i] = *(const short8*)(Asb + buf * 8192 + ro[i]);
            if (s < 31) gen_store(s + 1, buf ^ 1);
#pragma unroll
            for (int i = 0; i < 4; ++i)
#pragma unroll
                for (int j = 0; j < 2; ++j)
                    acc[i][j] = mfma16(a[i], bfr[j], acc[i][j]);
#pragma unroll
            for (int i = 0; i < 4; ++i)
                a[i] = *(const short8*)(Asb + buf * 8192 + (ro[i] ^ 64));
#pragma unroll
            for (int i = 0; i < 4; ++i)
#pragma unroll
                for (int j = 0; j < 2; ++j)
                    acc[i][j] = mfma16(a[i], bfr[2 + j], acc[i][j]);
            __syncthreads();
        }
    }

    // ---- epilogue: h1 = small features + bias, LeakyReLU -> h1s (LDS bf16)
    // (xls/As dead after last loop barrier; h1s/xsm overlay them)
    if (t < 64) { xsm[t][0] = ax; xsm[t][1] = ay; xsm[t][2] = az; }
    const int c0 = w * 32 + lr, c1 = c0 + 16;
    const int c3 = w * 16 + lr;
    float cb0, cb1, cb3;   // b2/b3 pulled from colsml BEFORE h2s overwrites it
    {
        float c0v[7], c1v[7];
#pragma unroll
        for (int q = 0; q < 7; ++q) { c0v[q] = colsml[c0][q]; c1v[q] = colsml[c1][q]; }
        cb0 = c0v[6]; cb1 = c1v[6];
        cb3 = colsml[c3][7];
#pragma unroll
        for (int i = 0; i < 4; ++i) {
#pragma unroll
            for (int r = 0; r < 4; ++r) {
                int row = i * 16 + lq * 4 + r;
                float nrm = rowsml[row][0];
                float p0 = rowsml[row][1], p1 = rowsml[row][2];
                float p2 = rowsml[row][3], p3 = rowsml[row][4];
                float v0 = acc[i][0][r] + c0v[0] + nrm * c0v[1] +
                           p0 * c0v[2] + p1 * c0v[3] + p2 * c0v[4] + p3 * c0v[5];
                v0 = v0 > 0.f ? v0 : 0.01f * v0;
                h1s[row][c0] = f2bf(v0);
                float v1 = acc[i][1][r] + c1v[0] + nrm * c1v[1] +
                           p0 * c1v[2] + p1 * c1v[3] + p2 * c1v[4] + p3 * c1v[5];
                v1 = v1 > 0.f ? v1 : 0.01f * v1;
                h1s[row][c1] = f2bf(v1);
            }
        }
    }
    __syncthreads();

    // ---- phase 1: h2 = lrelu(h1s @ W2 + b2) -> h2s (overwrites colsml; safe)
#pragma unroll
    for (int i = 0; i < 4; ++i)
#pragma unroll
        for (int j = 0; j < 2; ++j) acc[i][j] = zero;
    {
        const u16* w2s = W2frag + t * 16;
#pragma unroll 2
        for (int kt = 0; kt < 8; ++kt) {
            short8 af[4], bfr[2];
#pragma unroll
            for (int i = 0; i < 4; ++i)
                af[i] = *(const short8*)&h1s[i * 16 + lr][kt * 32 + lq * 8];
#pragma unroll
            for (int j = 0; j < 2; ++j)
                bfr[j] = *(const short8*)(w2s + kt * 8192 + j * 8);
#pragma unroll
            for (int i = 0; i < 4; ++i)
#pragma unroll
                for (int j = 0; j < 2; ++j)
                    acc[i][j] = mfma16(af[i], bfr[j], acc[i][j]);
        }
#pragma unroll
        for (int i = 0; i < 4; ++i)
#pragma unroll
            for (int r = 0; r < 4; ++r) {
                int row = i * 16 + lq * 4 + r;
                float v0 = acc[i][0][r] + cb0;
                v0 = v0 > 0.f ? v0 : 0.01f * v0;
                h2s[row][c0] = f2bf(v0);
                float v1 = acc[i][1][r] + cb1;
                v1 = v1 > 0.f ? v1 : 0.01f * v1;
                h2s[row][c1] = f2bf(v1);
            }
    }
    __syncthreads();

    // ---- phase 2: fk = h2s @ W3 + b3, fused x outer-product reduce
    {
        floatx4 acc2[4];
#pragma unroll
        for (int i = 0; i < 4; ++i) acc2[i] = zero;
        const u16* w3s = W3frag + t * 8;
#pragma unroll 2
        for (int kt = 0; kt < 8; ++kt) {
            short8 af[4];
#pragma unroll
            for (int i = 0; i < 4; ++i)
                af[i] = *(const short8*)&h2s[i * 16 + lr][kt * 32 + lq * 8];
            short8 bfr = *(const short8*)(w3s + kt * 4096);
#pragma unroll
            for (int i = 0; i < 4; ++i) acc2[i] = mfma16(af[i], bfr, acc2[i]);
        }
        float s0 = 0.f, s1 = 0.f, s2 = 0.f;
#pragma unroll
        for (int i = 0; i < 4; ++i)
#pragma unroll
            for (int r = 0; r < 4; ++r) {
                int row = i * 16 + lq * 4 + r;
                float fk = acc2[i][r] + cb3;
                s0 += fk * xsm[row][0];
                s1 += fk * xsm[row][1];
                s2 += fk * xsm[row][2];
            }
        s0 += __shfl_xor(s0, 16); s0 += __shfl_xor(s0, 32);
        s1 += __shfl_xor(s1, 16); s1 += __shfl_xor(s1, 32);
        s2 += __shfl_xor(s2, 16); s2 += __shfl_xor(s2, 32);
        if (lq == 0) {  // lanes 0..15; cols wave-exclusive
            redm[c3][0] = s0; redm[c3][1] = s1; redm[c3][2] = s2;
        }
    }
    __syncthreads();
    if (t < 128) {
#pragma unroll
        for (int d = 0; d < 3; ++d)
            atomicAdd(&out[(b * 128 + t) * 3 + d], redm[t][d] * (1.0f / 2048.0f));
    }
}

extern "C" void kernel_launch(void* const* d_in, const int* in_sizes, int n_in,
                              void* d_out, int out_size, void* d_ws, size_t ws_size,
                              hipStream_t stream) {
    const float* x     = (const float*)d_in[0];
    const float* u     = (const float*)d_in[1];
    const float* basis = (const float*)d_in[2];
    const float* W1    = (const float*)d_in[3];
    const float* b1    = (const float*)d_in[4];
    const float* W2    = (const float*)d_in[5];
    const float* b2    = (const float*)d_in[6];
    const float* W3    = (const float*)d_in[7];
    const float* b3    = (const float*)d_in[8];
    float* out = (float*)d_out;

    char* ws = (char*)d_ws;
    u16*  W1frag = (u16*)ws;                      // 1,048,576 B
    u16*  W2frag = (u16*)(ws + 1048576);          //   131,072 B
    u16*  W3frag = (u16*)(ws + 1179648);          //    65,536 B

    k_prep<<<2432, 256, 0, stream>>>(W1, W2, W3, W1frag, W2frag, W3frag, out);
    k_fused<<<dim3(32, 16), 512, 0, stream>>>(x, u, basis, W1, b1, b2, b3,
                                              W1frag, W2frag, W3frag, out);
}